// Round 24
// baseline (64.409 us; speedup 1.0000x reference)
//
#include <hip/hip_runtime.h>

// CRF-RNN (C=2) on 56x56, 10 iterations in ONE kernel, plain launch.
// 196 blocks x 512 thr (8 waves = 2/SIMD), 1 block/CU.
//
// Math: s = sigmoid(q1-q0); d = (2u-1) - alpha - beta*t_sp/n_sp - gamma*t_bl/n_bl.
//  * spatial separable: row conv (wave w owns local-j cols {2w,2w+1}, lane=y,
//    s-row register-cached, weights wave-uniform/broadcast) + in-wave fold
//    (r24: single 7-shfl combined butterfly for both columns).
//  * bilateral: 128 intensity bins, counting sort ONCE, band +-5 bins
//    (all |dg|<=10 exact; excluded w<=1.7e-9). r24: trip INDICES and WEIGHTS
//    are register-cached at iter 0 (m_reg[10], w_reg[10]) -- iters 1..9 do
//    10 INDEPENDENT s_sh[m_reg[i]] reads + fma. The sorted s-view, the
//    per-sync rank-scatter (1.67M bank-conflict cycles on the sync critical
//    path), and rank[] are all DELETED. Tail (blen>320) recomputes exactly.
//  * norms s-independent: iter-0 computes them, reciprocals in registers.
//
// Sync (r15/r20, proven): zero-sentinel flow control, per-thread tight spin.
// Publish = leader lanes store right out of the reduce (relaxed agent scope
// -> LLC, no cache maintenance), no pre-barrier (detection of all-3136
// implies every wave everywhere finished reading old s_sh). Poll = re-issue
// 1-2 quad loads (sc0 sc1) immediately. Restage = contiguous linear write
// only + ONE barrier.

namespace {

constexpr int NPIX = 3136;
constexpr int WIMG = 56;
constexpr int JPB  = 16;              // j-pixels per block
constexpr int NBLK = NPIX / JPB;      // 196 blocks = 1 per CU
constexpr int NTHR = 512;             // 8 waves
constexpr int NQ   = NPIX / 4;        // 784 quads
constexpr int NBUF = 9;               // publish buffers (syncs after iters 0..8)
constexpr int Q2   = NQ - NTHR;       // 272 threads own a second quad
constexpr int NBIN = 128;             // intensity bins (2 levels each)
constexpr int BANDB = 5;              // band radius in bins (covers |dg|<=10)
constexpr int NCHK = 98;              // histogram chunks
constexpr int CPX  = 32;              // pixels per chunk
constexpr int UTRIP = 10;             // unrolled band trips (covers blen<=320)

constexpr float LOG2E = 1.4426950408889634f;
constexpr float C1 = -LOG2E / 18.0f;      // spatial exponent coeff
constexpr float C2 = -LOG2E / 51200.0f;   // bilateral spatial coeff
constexpr float C3 = -LOG2E / 6.0f;       // bilateral intensity coeff

// LDS pool layout (bytes, 16-aligned)
constexpr int O_SSH  = 0;         // float[3136] s, linear (init: H u16[98][128] lo)
constexpr int O_GXY  = 12544;     // float2[3136] {g, x+64y}, sorted (init: H hi)
constexpr int O_MSRT = 37632;     // u16[3136]  sorted pos -> linear pixel idx
constexpr int O_OFF  = 43904;     // u32[129]   bin offsets (pad 528)
constexpr int O_WSX  = 44432;     // float[16][56] per-j row weights (aligned)
constexpr int O_WSY  = 48016;     // float[16][56] per-j column weights
constexpr int O_LIDX = 51600;     // u8[3136]   rank within (chunk,bin)
constexpr int POOLSZ = 54736;

#define REDUCE32(v) \
    { v += __shfl_xor(v, 1); v += __shfl_xor(v, 2); v += __shfl_xor(v, 4); \
      v += __shfl_xor(v, 8); v += __shfl_xor(v, 16); }

__global__ __launch_bounds__(NTHR) void crf_all(
    const float* __restrict__ inp,
    const float* __restrict__ spw, const float* __restrict__ blw,
    const float* __restrict__ cmw,
    float* sbufs, float* __restrict__ out)
{
    __shared__ __align__(16) unsigned char pool[POOLSZ];
    float*  s_sh  = (float*)(pool + O_SSH);
    float4* s_sh4 = (float4*)(pool + O_SSH);
    float2* gxy   = (float2*)(pool + O_GXY);
    unsigned short* m_srt = (unsigned short*)(pool + O_MSRT);
    unsigned*       offs  = (unsigned*)(pool + O_OFF);
    float*  wsx   = (float*)(pool + O_WSX);
    float*  wsy   = (float*)(pool + O_WSY);
    unsigned char*  lidx = (unsigned char*)(pool + O_LIDX);
    unsigned short* H  = (unsigned short*)(pool + O_SSH);   // init union (25088B)
    unsigned*       Hz = (unsigned*)(pool + O_SSH);

    const int t   = threadIdx.x;
    const int bid = blockIdx.x;
    const int sub = t & 31;
    const int jl  = t >> 5;               // 0..15
    const int j   = bid * JPB + jl;
    const int xj  = j % WIMG;             // blocks may straddle rows (16 ∤ 56)
    const int yj  = j / WIMG;
    const float xjf = (float)xj, yjf = (float)yj;

    const float uj = inp[j];
    const float gj = inp[NPIX + j] * 255.0f;

    // collapse the 2x2 weight matrices to 3 scalars
    const float e0 = cmw[2] - cmw[0];
    const float e1 = cmw[3] - cmw[1];
    const float alpha = e0 * (spw[0] + blw[0]) + e1 * (spw[2] + blw[2]);
    const float beta  = e0 * (spw[1] - spw[0]) + e1 * (spw[3] - spw[2]);
    const float gamma = e0 * (blw[1] - blw[0]) + e1 * (blw[3] - blw[2]);

    // ---- I0: zero H; build aligned per-j weight tables (outside H region)
    for (int i = t; i < 6272; i += NTHR) Hz[i] = 0u;
    for (int idx = t; idx < JPB * 56; idx += NTHR) {
        const int jlw = idx / 56, p = idx - jlw * 56;
        const int jj = bid * JPB + jlw;
        const float ddx = (float)(jj % WIMG - p);
        const float ddy = (float)(jj / WIMG - p);
        wsx[idx] = __builtin_amdgcn_exp2f(C1 * ddx * ddx);
        wsy[idx] = __builtin_amdgcn_exp2f(C1 * ddy * ddy);
    }
    __syncthreads();
    // ---- I1: per-chunk histogram, saving local index (98 chunks x 32 px)
    if (t < NCHK) {
        unsigned short* Hr = H + t * NBIN;
        const int mb = t * CPX;
        for (int i = 0; i < CPX; ++i) {
            int b = (int)(inp[NPIX + mb + i] * 255.0f);
            b = (b > 255 ? 255 : b) >> 1;
            lidx[mb + i] = (unsigned char)Hr[b];
            Hr[b] = (unsigned short)(Hr[b] + 1);
        }
    }
    __syncthreads();
    // ---- I2: column prefix per bin over chunks; totals -> offs[b]
    if (t < NBIN) {
        unsigned run = 0;
        for (int c = 0; c < NCHK; ++c) {
            unsigned short v = H[c * NBIN + t];
            H[c * NBIN + t] = (unsigned short)run;
            run += v;
        }
        offs[t] = run;
    }
    __syncthreads();
    // ---- I3: exclusive scan offs[0..127] (one wave, 2 bins/lane)
    if (t < 64) {
        unsigned v0 = offs[2 * t], v1 = offs[2 * t + 1];
        unsigned sum = v0 + v1;
        unsigned sc = sum;
        for (int d = 1; d < 64; d <<= 1) {
            unsigned n = __shfl_up(sc, d);
            if (t >= d) sc += n;
        }
        unsigned base = sc - sum;
        offs[2 * t] = base;
        offs[2 * t + 1] = base + v0;
        if (t == 63) offs[NBIN] = sc;              // = 3136
    }
    __syncthreads();
    // ---- I4: PARALLEL ranks -> m_srt (read-only pass)
    for (int m = t; m < NPIX; m += NTHR) {
        int b = (int)(inp[NPIX + m] * 255.0f);
        b = (b > 255 ? 255 : b) >> 1;
        const int r = (int)offs[b] + (int)H[(m >> 5) * NBIN + b] + (int)lidx[m];
        m_srt[r] = (unsigned short)m;
    }
    __syncthreads();
    // ---- I5: H dead. Fill gxy (sorted) + s_sh = u (linear).
    for (int p = t; p < NPIX; p += NTHR) {
        const int m = (int)m_srt[p];
        const int yi = (m * 9363) >> 19;   // m/56 (exact for m<3136)
        const int xi = m - yi * 56;
        gxy[p] = make_float2(inp[NPIX + m] * 255.0f, (float)(xi + 64 * yi));
    }
    {
        const float4* u4 = (const float4*)inp;
        for (int q = t; q < NQ; q += NTHR) s_sh4[q] = u4[q];
    }
    __syncthreads();

    // n_sp = Sx*Sy (exact separable)
    float sx, sy;
    {
        float dd = xjf - (float)sub;
        sx = __builtin_amdgcn_exp2f(C1 * dd * dd);
        if (sub + 32 < 56) {
            float d2 = xjf - (float)(sub + 32);
            sx += __builtin_amdgcn_exp2f(C1 * d2 * d2);
        }
        REDUCE32(sx);
        dd = yjf - (float)sub;
        sy = __builtin_amdgcn_exp2f(C1 * dd * dd);
        if (sub + 32 < 56) {
            float d2 = yjf - (float)(sub + 32);
            sy += __builtin_amdgcn_exp2f(C1 * d2 * d2);
        }
        REDUCE32(sy);
    }
    const float rnsp = 1.0f / (sx * sy);

    int bj = (int)gj; bj = (bj > 255 ? 255 : bj) >> 1;
    const int b0 = bj < BANDB ? 0 : bj - BANDB;
    const int b1 = bj + BANDB > NBIN - 1 ? NBIN - 1 : bj + BANDB;
    const int blo = (int)offs[b0];
    const int bhi = (int)offs[b1 + 1];

    // spatial: wave w computes cols {2w,2w+1} (lane=y, s-row reg-cached,
    // uniform weight reads); fold via ONE combined 7-shfl butterfly.
    auto spatial = [&]() -> float {
        const int wv = t >> 6;              // wave id 0..7
        const int ln = t & 63;              // lane = y
        float v0 = 0.f, v1 = 0.f;
        if (ln < 56) {
            const float4* S = s_sh4 + ln * 14;
            float4 sv[14];
#pragma unroll
            for (int q = 0; q < 14; ++q) sv[q] = S[q];
            const int c0 = wv * 2, c1 = c0 + 1;
            const float4* R0 = (const float4*)(wsx + c0 * 56);  // uniform
            const float4* R1 = (const float4*)(wsx + c1 * 56);
            float a0 = 0.f, a1 = 0.f;
#pragma unroll
            for (int q = 0; q < 14; ++q) {
                float4 w0 = R0[q], w1 = R1[q];
                a0 = fmaf(w0.x, sv[q].x, a0); a0 = fmaf(w0.y, sv[q].y, a0);
                a0 = fmaf(w0.z, sv[q].z, a0); a0 = fmaf(w0.w, sv[q].w, a0);
                a1 = fmaf(w1.x, sv[q].x, a1); a1 = fmaf(w1.y, sv[q].y, a1);
                a1 = fmaf(w1.z, sv[q].z, a1); a1 = fmaf(w1.w, sv[q].w, a1);
            }
            v0 = wsy[c0 * 56 + ln] * a0;    // column weight for y=ln
            v1 = wsy[c1 * 56 + ln] * a1;
        }
        // combined fold: pre-fold both across halves, select, 5-step butterfly
        v0 += __shfl_xor(v0, 32);
        v1 += __shfl_xor(v1, 32);
        float z = (ln < 32) ? v0 : v1;      // lanes 0-31: col 2w; 32-63: 2w+1
        z += __shfl_xor(z, 1); z += __shfl_xor(z, 2); z += __shfl_xor(z, 4);
        z += __shfl_xor(z, 8); z += __shfl_xor(z, 16);
        return z;
    };

    int   m_reg[UTRIP];                    // cached trip indices (linear m)
    float w_reg[UTRIP];                    // cached trip weights

    // iter-0 bilateral: computes weights (masked), caches {m,w} in REGISTERS,
    // accumulates n_bl. s_sh holds u (linear).
    auto bilateral0 = [&](float* nacc_out) -> float {
        float acc = 0.f, nacc = 0.f;
        const int pb = blo + sub;
#pragma unroll
        for (int i = 0; i < UTRIP; ++i) {
            const int pp = pb + i * 32;
            const int pc = pp < bhi ? pp : bhi - 1;     // clamp (bhi > blo)
            const float2 gx = gxy[pc];
            const int   m  = (int)m_srt[pc];
            const float yi  = floorf(gx.y * 0.015625f);
            const float xi  = fmaf(-64.f, yi, gx.y);
            const float ux = xi - xjf, vy = yi - yjf;
            const float r2 = fmaf(ux, ux, vy * vy);
            const float dg = gx.x - gj;
            float w = __builtin_amdgcn_exp2f(fmaf(dg * C3, dg, r2 * C2));
            w = (pp < bhi) ? w : 0.0f;                  // mask out-of-band
            m_reg[i] = m;
            w_reg[i] = w;
            acc = fmaf(w, s_sh[m], acc);
            nacc += w;
        }
        for (int pp = pb + UTRIP * 32; pp < bhi; pp += 32) {  // rare tail
            const float2 gx = gxy[pp];
            const float sv  = s_sh[(int)m_srt[pp]];
            const float yi  = floorf(gx.y * 0.015625f);
            const float xi  = fmaf(-64.f, yi, gx.y);
            const float ux = xi - xjf, vy = yi - yjf;
            const float r2 = fmaf(ux, ux, vy * vy);
            const float dg = gx.x - gj;
            const float w = __builtin_amdgcn_exp2f(fmaf(dg * C3, dg, r2 * C2));
            acc = fmaf(w, sv, acc);
            nacc += w;
        }
        REDUCE32(acc); REDUCE32(nacc);
        *nacc_out = nacc;
        return acc;
    };

    // iters 1..9 bilateral: 10 INDEPENDENT register-addressed s_sh reads + fma
    auto bilateralK = [&]() -> float {
        float acc = 0.f;
#pragma unroll
        for (int i = 0; i < UTRIP; ++i)
            acc = fmaf(w_reg[i], s_sh[m_reg[i]], acc);
        const int pb = blo + sub;
        for (int pp = pb + UTRIP * 32; pp < bhi; pp += 32) {  // rare tail
            const float2 gx = gxy[pp];
            const float sv  = s_sh[(int)m_srt[pp]];
            const float yi  = floorf(gx.y * 0.015625f);
            const float xi  = fmaf(-64.f, yi, gx.y);
            const float ux = xi - xjf, vy = yi - yjf;
            const float r2 = fmaf(ux, ux, vy * vy);
            const float dg = gx.x - gj;
            const float w = __builtin_amdgcn_exp2f(fmaf(dg * C3, dg, r2 * C2));
            acc = fmaf(w, sv, acc);
        }
        REDUCE32(acc);
        return acc;
    };

    // publish LINEAR (leader, right out of the reduce, no pre-barrier) +
    // per-thread tight zero-sentinel spin + contiguous restage + ONE barrier.
    auto publish_sync = [&](float s, float* buf) {
        if (sub == 0)
            __hip_atomic_store(&buf[j], s, __ATOMIC_RELAXED,
                               __HIP_MEMORY_SCOPE_AGENT);
        const float4* src = (const float4*)buf;
        float4 a, b;
        const bool two = (t < Q2);
        bool da = false, db = !two;
        for (;;) {
            if (!da)
                asm volatile("global_load_dwordx4 %0, %1, off sc0 sc1"
                             : "=&v"(a) : "v"(src + t));
            if (!db)
                asm volatile("global_load_dwordx4 %0, %1, off sc0 sc1"
                             : "=&v"(b) : "v"(src + NTHR + t));
            asm volatile("s_waitcnt vmcnt(0)" ::: "memory");
            if (!da) da = (fminf(fminf(a.x, a.y), fminf(a.z, a.w)) != 0.0f);
            if (!db) db = (fminf(fminf(b.x, b.y), fminf(b.z, b.w)) != 0.0f);
            if (da && db) break;                    // exec mask narrows wave
        }
        s_sh4[t] = a;                               // contiguous restage only
        if (two) s_sh4[NTHR + t] = b;
        __syncthreads();                            // s_sh fully fresh
    };

    const float base = 2.0f * uj - 1.0f - alpha;
    float rnbl, s;

    // ---- iteration 0 (s = u): caches {m,w}, accumulates n_bl
    {
        float tsp = spatial();
        float nacc;
        float acc = bilateral0(&nacc);
        rnbl = 1.0f / nacc;
        float d = base - beta * (tsp * rnsp) - gamma * (acc * rnbl);
        s = 1.0f / (1.0f + __builtin_amdgcn_exp2f(-d * LOG2E));
    }
    publish_sync(s, sbufs);

    // ---- iterations 1..9
    for (int k = 1; k < 10; ++k) {
        float tsp = spatial();
        float acc = bilateralK();
        float d = base - beta * (tsp * rnsp) - gamma * (acc * rnbl);
        s = 1.0f / (1.0f + __builtin_amdgcn_exp2f(-d * LOG2E));
        if (k < 9) publish_sync(s, sbufs + k * NPIX);
        else if (sub == 0) out[j] = s;   // softmax(q)[1] = sigmoid(d)
    }
}

}  // namespace

extern "C" void kernel_launch(void* const* d_in, const int* in_sizes, int n_in,
                              void* d_out, int out_size, void* d_ws, size_t ws_size,
                              hipStream_t stream) {
    const float* inp = (const float*)d_in[0];
    const float* spw = (const float*)d_in[1];
    const float* blw = (const float*)d_in[2];
    const float* cmw = (const float*)d_in[3];
    float* sbufs = (float*)d_ws;          // 9 x 3136 floats, zero = "not yet"
    float* out = (float*)d_out;

    hipMemsetAsync(sbufs, 0, NBUF * NPIX * sizeof(float), stream);
    crf_all<<<dim3(NBLK), dim3(NTHR), 0, stream>>>(inp, spw, blw, cmw,
                                                   sbufs, out);
}

// Round 25
// 55.738 us; speedup vs baseline: 1.1556x; 1.1556x over previous
//
#include <hip/hip_runtime.h>

// CRF-RNN (C=2) on 56x56, 10 iterations in ONE kernel, plain launch.
// 196 blocks x 512 thr (8 waves = 2/SIMD), 1 block/CU.  Base = r23 (best).
//
// Math: s = sigmoid(q1-q0); d = (2u-1) - alpha - beta*t_sp/n_sp - gamma*t_bl/n_bl.
//  * spatial separable: row conv over a 10-QUAD WINDOW (r25: wave-uniform
//    runtime base, compile-time trip count -> full ILP; covers all |dx|<=16
//    for both of the wave's columns; omitted weights <= 1.1e-7) + in-wave
//    weighted 64-lane butterfly fold. n_sp = Sx*Sy exactly.
//  * bilateral: 128 intensity bins, counting sort ONCE, band +-5 bins
//    (all |dg|<=10 exact). Iter-0 caches per-pair weights in wband[16][320];
//    iters 1..9: {load w, load s_srt contiguous, fma}. Tail recomputes.
//  * norms s-independent: iter-0 computes them, reciprocals in registers.
//
// Sync (r15/r20, proven): zero-sentinel flow control, per-thread tight spin.
// Publish = leader lanes store right out of the reduce (relaxed agent scope
// -> LLC, no cache maintenance), no pre-barrier. Poll = re-issue 1-2 quad
// loads (sc0 sc1) immediately. Restage (linear + rank-scatter) + ONE barrier.
// (r24's register-indexed band reads REVERTED: random per-lane s_sh reads
// cost more in conflicts than the once-per-sync scatter they deleted.)

namespace {

constexpr int NPIX = 3136;
constexpr int WIMG = 56;
constexpr int JPB  = 16;              // j-pixels per block
constexpr int NBLK = NPIX / JPB;      // 196 blocks = 1 per CU
constexpr int NTHR = 512;             // 8 waves
constexpr int NQ   = NPIX / 4;        // 784 quads
constexpr int NBUF = 9;               // publish buffers (syncs after iters 0..8)
constexpr int Q2   = NQ - NTHR;       // 272 threads own a second quad
constexpr int NBIN = 128;             // intensity bins (2 levels each)
constexpr int BANDB = 5;              // band radius in bins (covers |dg|<=10)
constexpr int NCHK = 98;              // histogram chunks
constexpr int CPX  = 32;              // pixels per chunk
constexpr int UTRIP = 10;             // unrolled band trips (covers blen<=320)
constexpr int SQW  = 10;              // spatial window quads

constexpr float LOG2E = 1.4426950408889634f;
constexpr float C1 = -LOG2E / 18.0f;      // spatial exponent coeff
constexpr float C2 = -LOG2E / 51200.0f;   // bilateral spatial coeff
constexpr float C3 = -LOG2E / 6.0f;       // bilateral intensity coeff

// LDS pool layout (bytes, 16-aligned)
constexpr int O_SSH  = 0;         // float[3136] s, linear (init: H u16[98][128] lo)
constexpr int O_SSRT = 12544;     // float[3136] s, sorted (init: H hi)
constexpr int O_GXY  = 25088;     // float2[3136] {g, x+64y}, sorted
constexpr int O_MSRT = 50176;     // u16[3136]  sorted pos -> linear pixel idx
constexpr int O_RANK = 56448;     // u16[3136]  linear pixel -> sorted pos
constexpr int O_OFF  = 62720;     // u32[129]   bin offsets (pad 528)
constexpr int O_WSX  = 63248;     // float[16][56] per-j row weights (aligned)
constexpr int O_WSY  = 66832;     // float[16][56] per-j column weights
constexpr int O_LIDX = 70416;     // u8[3136]   rank within (chunk,bin)
constexpr int O_WBND = 73552;     // float[16][320] cached bilateral weights
constexpr int POOLSZ = 94032;

#define REDUCE32(v) \
    { v += __shfl_xor(v, 1); v += __shfl_xor(v, 2); v += __shfl_xor(v, 4); \
      v += __shfl_xor(v, 8); v += __shfl_xor(v, 16); }
#define REDUCE64(v) \
    { v += __shfl_xor(v, 1); v += __shfl_xor(v, 2); v += __shfl_xor(v, 4); \
      v += __shfl_xor(v, 8); v += __shfl_xor(v, 16); v += __shfl_xor(v, 32); }

__global__ __launch_bounds__(NTHR) void crf_all(
    const float* __restrict__ inp,
    const float* __restrict__ spw, const float* __restrict__ blw,
    const float* __restrict__ cmw,
    float* sbufs, float* __restrict__ out)
{
    __shared__ __align__(16) unsigned char pool[POOLSZ];
    float*  s_sh  = (float*)(pool + O_SSH);
    float4* s_sh4 = (float4*)(pool + O_SSH);
    float*  s_srt = (float*)(pool + O_SSRT);
    float2* gxy   = (float2*)(pool + O_GXY);
    unsigned short* m_srt = (unsigned short*)(pool + O_MSRT);
    unsigned short* rank  = (unsigned short*)(pool + O_RANK);
    unsigned*       offs  = (unsigned*)(pool + O_OFF);
    float*  wsx   = (float*)(pool + O_WSX);
    float*  wsy   = (float*)(pool + O_WSY);
    unsigned char*  lidx = (unsigned char*)(pool + O_LIDX);
    float*  wband = (float*)(pool + O_WBND);
    unsigned short* H  = (unsigned short*)(pool + O_SSH);   // init union (25088B)
    unsigned*       Hz = (unsigned*)(pool + O_SSH);

    const int t   = threadIdx.x;
    const int bid = blockIdx.x;
    const int sub = t & 31;
    const int jl  = t >> 5;               // 0..15
    const int j   = bid * JPB + jl;
    const int xj  = j % WIMG;             // blocks may straddle rows (16 ∤ 56)
    const int yj  = j / WIMG;
    const float xjf = (float)xj, yjf = (float)yj;

    const float uj = inp[j];
    const float gj = inp[NPIX + j] * 255.0f;

    // collapse the 2x2 weight matrices to 3 scalars
    const float e0 = cmw[2] - cmw[0];
    const float e1 = cmw[3] - cmw[1];
    const float alpha = e0 * (spw[0] + blw[0]) + e1 * (spw[2] + blw[2]);
    const float beta  = e0 * (spw[1] - spw[0]) + e1 * (spw[3] - spw[2]);
    const float gamma = e0 * (blw[1] - blw[0]) + e1 * (blw[3] - blw[2]);

    // ---- I0: zero H; build aligned per-j weight tables (outside H region)
    for (int i = t; i < 6272; i += NTHR) Hz[i] = 0u;
    for (int idx = t; idx < JPB * 56; idx += NTHR) {
        const int jlw = idx / 56, p = idx - jlw * 56;
        const int jj = bid * JPB + jlw;
        const float ddx = (float)(jj % WIMG - p);
        const float ddy = (float)(jj / WIMG - p);
        wsx[idx] = __builtin_amdgcn_exp2f(C1 * ddx * ddx);
        wsy[idx] = __builtin_amdgcn_exp2f(C1 * ddy * ddy);
    }
    __syncthreads();
    // ---- I1: per-chunk histogram, saving local index (98 chunks x 32 px)
    if (t < NCHK) {
        unsigned short* Hr = H + t * NBIN;
        const int mb = t * CPX;
        for (int i = 0; i < CPX; ++i) {
            int b = (int)(inp[NPIX + mb + i] * 255.0f);
            b = (b > 255 ? 255 : b) >> 1;
            lidx[mb + i] = (unsigned char)Hr[b];
            Hr[b] = (unsigned short)(Hr[b] + 1);
        }
    }
    __syncthreads();
    // ---- I2: column prefix per bin over chunks; totals -> offs[b]
    if (t < NBIN) {
        unsigned run = 0;
        for (int c = 0; c < NCHK; ++c) {
            unsigned short v = H[c * NBIN + t];
            H[c * NBIN + t] = (unsigned short)run;
            run += v;
        }
        offs[t] = run;
    }
    __syncthreads();
    // ---- I3: exclusive scan offs[0..127] (one wave, 2 bins/lane)
    if (t < 64) {
        unsigned v0 = offs[2 * t], v1 = offs[2 * t + 1];
        unsigned sum = v0 + v1;
        unsigned sc = sum;
        for (int d = 1; d < 64; d <<= 1) {
            unsigned n = __shfl_up(sc, d);
            if (t >= d) sc += n;
        }
        unsigned base = sc - sum;
        offs[2 * t] = base;
        offs[2 * t + 1] = base + v0;
        if (t == 63) offs[NBIN] = sc;              // = 3136
    }
    __syncthreads();
    // ---- I4: PARALLEL ranks -> m_srt + inverse rank[] (read-only pass)
    for (int m = t; m < NPIX; m += NTHR) {
        int b = (int)(inp[NPIX + m] * 255.0f);
        b = (b > 255 ? 255 : b) >> 1;
        const int r = (int)offs[b] + (int)H[(m >> 5) * NBIN + b] + (int)lidx[m];
        m_srt[r] = (unsigned short)m;
        rank[m]  = (unsigned short)r;
    }
    __syncthreads();
    // ---- I5: H dead. Fill sorted arrays + s_sh = u (linear).
    for (int p = t; p < NPIX; p += NTHR) {
        const int m = (int)m_srt[p];
        s_srt[p] = inp[m];                 // iter-0 s = u, sorted
        const int yi = (m * 9363) >> 19;   // m/56 (exact for m<3136)
        const int xi = m - yi * 56;
        gxy[p] = make_float2(inp[NPIX + m] * 255.0f, (float)(xi + 64 * yi));
    }
    {
        const float4* u4 = (const float4*)inp;
        for (int q = t; q < NQ; q += NTHR) s_sh4[q] = u4[q];
    }
    __syncthreads();

    // n_sp = Sx*Sy (exact separable)
    float sx, sy;
    {
        float dd = xjf - (float)sub;
        sx = __builtin_amdgcn_exp2f(C1 * dd * dd);
        if (sub + 32 < 56) {
            float d2 = xjf - (float)(sub + 32);
            sx += __builtin_amdgcn_exp2f(C1 * d2 * d2);
        }
        REDUCE32(sx);
        dd = yjf - (float)sub;
        sy = __builtin_amdgcn_exp2f(C1 * dd * dd);
        if (sub + 32 < 56) {
            float d2 = yjf - (float)(sub + 32);
            sy += __builtin_amdgcn_exp2f(C1 * d2 * d2);
        }
        REDUCE32(sy);
    }
    const float rnsp = 1.0f / (sx * sy);

    int bj = (int)gj; bj = (bj > 255 ? 255 : bj) >> 1;
    const int b0 = bj < BANDB ? 0 : bj - BANDB;
    const int b1 = bj + BANDB > NBIN - 1 ? NBIN - 1 : bj + BANDB;
    const int blo = (int)offs[b0];
    const int bhi = (int)offs[b1 + 1];

    // spatial: wave w computes cols {2w,2w+1} over a 10-quad window (covers
    // |dx|<=16 for both; base wave-uniform, trips compile-time -> full ILP);
    // fold IN-WAVE via weighted 64-lane butterfly.
    const int c0 = (t >> 6) * 2, c1 = c0 + 1;
    const int X0 = (bid * JPB + c0) % WIMG;
    int qlo = (X0 > 16) ? ((X0 - 16) >> 2) : 0;
    qlo = qlo > 14 - SQW ? 14 - SQW : qlo;
    auto spatial = [&]() -> float {
        const int ln = t & 63;              // lane = y
        float v0 = 0.f, v1 = 0.f;
        if (ln < 56) {
            const float4* S = s_sh4 + ln * 14 + qlo;
            float4 sv[SQW];
#pragma unroll
            for (int q = 0; q < SQW; ++q) sv[q] = S[q];
            const float4* R0 = (const float4*)(wsx + c0 * 56) + qlo; // uniform
            const float4* R1 = (const float4*)(wsx + c1 * 56) + qlo;
            float a0 = 0.f, a1 = 0.f;
#pragma unroll
            for (int q = 0; q < SQW; ++q) {
                float4 w0 = R0[q], w1 = R1[q];
                a0 = fmaf(w0.x, sv[q].x, a0); a0 = fmaf(w0.y, sv[q].y, a0);
                a0 = fmaf(w0.z, sv[q].z, a0); a0 = fmaf(w0.w, sv[q].w, a0);
                a1 = fmaf(w1.x, sv[q].x, a1); a1 = fmaf(w1.y, sv[q].y, a1);
                a1 = fmaf(w1.z, sv[q].z, a1); a1 = fmaf(w1.w, sv[q].w, a1);
            }
            v0 = wsy[c0 * 56 + ln] * a0;    // column weight for y=ln
            v1 = wsy[c1 * 56 + ln] * a1;
        }
        REDUCE64(v0); REDUCE64(v1);
        return ((t & 63) < 32) ? v0 : v1;   // lanes 0-31: 2w; 32-63: 2w+1
    };

    // iter-0 bilateral: computes weights (masked), CACHES them, builds n_bl
    auto bilateral0 = [&](float* nacc_out) -> float {
        float acc = 0.f, nacc = 0.f;
        const int pb = blo + sub;
        float* wb = wband + jl * (UTRIP * 32);
#pragma unroll
        for (int i = 0; i < UTRIP; ++i) {
            const int pp = pb + i * 32;
            const int pc = pp < bhi ? pp : bhi - 1;     // clamp (bhi > blo)
            const float2 gx = gxy[pc];
            const float sv  = s_srt[pc];
            const float yi  = floorf(gx.y * 0.015625f);
            const float xi  = fmaf(-64.f, yi, gx.y);
            const float ux = xi - xjf, vy = yi - yjf;
            const float r2 = fmaf(ux, ux, vy * vy);
            const float dg = gx.x - gj;
            float w = __builtin_amdgcn_exp2f(fmaf(dg * C3, dg, r2 * C2));
            w = (pp < bhi) ? w : 0.0f;                  // mask out-of-band
            wb[i * 32 + sub] = w;                       // cache (invariant)
            acc = fmaf(w, sv, acc);
            nacc += w;
        }
        for (int pp = pb + UTRIP * 32; pp < bhi; pp += 32) {  // rare tail
            const float2 gx = gxy[pp];
            const float sv  = s_srt[pp];
            const float yi  = floorf(gx.y * 0.015625f);
            const float xi  = fmaf(-64.f, yi, gx.y);
            const float ux = xi - xjf, vy = yi - yjf;
            const float r2 = fmaf(ux, ux, vy * vy);
            const float dg = gx.x - gj;
            const float w = __builtin_amdgcn_exp2f(fmaf(dg * C3, dg, r2 * C2));
            acc = fmaf(w, sv, acc);
            nacc += w;
        }
        REDUCE32(acc); REDUCE32(nacc);
        *nacc_out = nacc;
        return acc;
    };

    // iters 1..9 bilateral: {load cached w, load s, fma} -- no exp2/geometry
    auto bilateralK = [&]() -> float {
        float acc = 0.f;
        const int pb = blo + sub;
        const float* wb = wband + jl * (UTRIP * 32);
#pragma unroll
        for (int i = 0; i < UTRIP; ++i) {
            const int pp = pb + i * 32;
            const int pc = pp < bhi ? pp : bhi - 1;
            const float w  = wb[i * 32 + sub];          // 0 for masked trips
            const float sv = s_srt[pc];
            acc = fmaf(w, sv, acc);
        }
        for (int pp = pb + UTRIP * 32; pp < bhi; pp += 32) {  // rare tail
            const float2 gx = gxy[pp];
            const float sv  = s_srt[pp];
            const float yi  = floorf(gx.y * 0.015625f);
            const float xi  = fmaf(-64.f, yi, gx.y);
            const float ux = xi - xjf, vy = yi - yjf;
            const float r2 = fmaf(ux, ux, vy * vy);
            const float dg = gx.x - gj;
            const float w = __builtin_amdgcn_exp2f(fmaf(dg * C3, dg, r2 * C2));
            acc = fmaf(w, sv, acc);
        }
        REDUCE32(acc);
        return acc;
    };

    // publish LINEAR (leader, right out of the reduce, no pre-barrier) +
    // per-thread tight zero-sentinel spin + restage: linear write + rank-
    // scatter into s_srt + ONE barrier.
    auto publish_sync = [&](float s, float* buf) {
        if (sub == 0)
            __hip_atomic_store(&buf[j], s, __ATOMIC_RELAXED,
                               __HIP_MEMORY_SCOPE_AGENT);
        const float4* src = (const float4*)buf;
        float4 a, b;
        const bool two = (t < Q2);
        bool da = false, db = !two;
        for (;;) {
            if (!da)
                asm volatile("global_load_dwordx4 %0, %1, off sc0 sc1"
                             : "=&v"(a) : "v"(src + t));
            if (!db)
                asm volatile("global_load_dwordx4 %0, %1, off sc0 sc1"
                             : "=&v"(b) : "v"(src + NTHR + t));
            asm volatile("s_waitcnt vmcnt(0)" ::: "memory");
            if (!da) da = (fminf(fminf(a.x, a.y), fminf(a.z, a.w)) != 0.0f);
            if (!db) db = (fminf(fminf(b.x, b.y), fminf(b.z, b.w)) != 0.0f);
            if (da && db) break;                    // exec mask narrows wave
        }
        s_sh4[t] = a;                               // linear restage
        {
            const int p4 = 4 * t;                   // sorted-view scatter
            s_srt[rank[p4 + 0]] = a.x;
            s_srt[rank[p4 + 1]] = a.y;
            s_srt[rank[p4 + 2]] = a.z;
            s_srt[rank[p4 + 3]] = a.w;
        }
        if (two) {
            s_sh4[NTHR + t] = b;
            const int p4 = 4 * (NTHR + t);
            s_srt[rank[p4 + 0]] = b.x;
            s_srt[rank[p4 + 1]] = b.y;
            s_srt[rank[p4 + 2]] = b.z;
            s_srt[rank[p4 + 3]] = b.w;
        }
        __syncthreads();                            // both views fresh
    };

    const float base = 2.0f * uj - 1.0f - alpha;
    float rnbl, s;

    // ---- iteration 0 (s = u): caches weights, accumulates n_bl
    {
        float tsp = spatial();
        float nacc;
        float acc = bilateral0(&nacc);
        rnbl = 1.0f / nacc;
        float d = base - beta * (tsp * rnsp) - gamma * (acc * rnbl);
        s = 1.0f / (1.0f + __builtin_amdgcn_exp2f(-d * LOG2E));
    }
    publish_sync(s, sbufs);

    // ---- iterations 1..9
    for (int k = 1; k < 10; ++k) {
        float tsp = spatial();
        float acc = bilateralK();
        float d = base - beta * (tsp * rnsp) - gamma * (acc * rnbl);
        s = 1.0f / (1.0f + __builtin_amdgcn_exp2f(-d * LOG2E));
        if (k < 9) publish_sync(s, sbufs + k * NPIX);
        else if (sub == 0) out[j] = s;   // softmax(q)[1] = sigmoid(d)
    }
}

}  // namespace

extern "C" void kernel_launch(void* const* d_in, const int* in_sizes, int n_in,
                              void* d_out, int out_size, void* d_ws, size_t ws_size,
                              hipStream_t stream) {
    const float* inp = (const float*)d_in[0];
    const float* spw = (const float*)d_in[1];
    const float* blw = (const float*)d_in[2];
    const float* cmw = (const float*)d_in[3];
    float* sbufs = (float*)d_ws;          // 9 x 3136 floats, zero = "not yet"
    float* out = (float*)d_out;

    hipMemsetAsync(sbufs, 0, NBUF * NPIX * sizeof(float), stream);
    crf_all<<<dim3(NBLK), dim3(NTHR), 0, stream>>>(inp, spw, blw, cmw,
                                                   sbufs, out);
}